// Round 4
// baseline (140.082 us; speedup 1.0000x reference)
//
#include <hip/hip_runtime.h>
#include <math.h>

#define BLOCK 256
// 16 lanes cooperate on one sample; lane `sub` owns quadrature points i = m*16 + sub.

__device__ __forceinline__ float exp2_fast(float x) {
#if __has_builtin(__builtin_amdgcn_exp2f)
    return __builtin_amdgcn_exp2f(x);   // bare v_exp_f32
#else
    return __expf(x * 0.69314718055994531f);
#endif
}

__global__ __launch_bounds__(BLOCK) void lbd_kernel(
    const int* __restrict__ uid_in, const int* __restrict__ iid_in,
    const float* __restrict__ uf,  const float* __restrict__ vf,
    const float* __restrict__ ubt, const float* __restrict__ ibt,
    const float* __restrict__ uae, const float* __restrict__ ube,
    const float* __restrict__ iae, const float* __restrict__ ibe,
    const float* __restrict__ gbp, float* __restrict__ out, int B)
{
    const int tid = threadIdx.x;
    const int sub = tid & 15;                       // lane within 16-lane sample group
    const int s0  = blockIdx.x * (BLOCK / 16) + (tid >> 4);
    const bool valid = (s0 < B);
    const int s = valid ? s0 : (B - 1);             // clamp: keep all lanes live for shuffles

    const int u = uid_in[s];
    const int v = iid_in[s];

    // ---- coalesced feature gather: lane sub reads elements sub, sub+16, ... ----
    const long long ub = (long long)u * 65;
    const long long vb = (long long)v * 65;
    float fu0 = uf[ub + sub],      fv0 = vf[vb + sub];
    float fu1 = uf[ub + 16 + sub], fv1 = vf[vb + 16 + sub];
    float fu2 = uf[ub + 32 + sub], fv2 = vf[vb + 32 + sub];
    float fu3 = uf[ub + 48 + sub], fv3 = vf[vb + 48 + sub];

    float dotp = fu0 * fv0 + fu1 * fv1 + fu2 * fv2 + fu3 * fv3;
    float sup  = fu0 * fu0 + fu1 * fu1 + fu2 * fu2 + fu3 * fu3;
    float svp  = fv0 * fv0 + fv1 * fv1 + fv2 * fv2 + fv3 * fv3;
#pragma unroll
    for (int d = 1; d < 16; d <<= 1) {              // butterfly within 16-group
        dotp += __shfl_xor(dotp, d, 64);
        sup  += __shfl_xor(sup,  d, 64);
        svp  += __shfl_xor(svp,  d, 64);
    }

    // ---- alpha / beta (smooth; all 16 lanes redundantly) ----------------------
    const float gb = gbp[0];
    const float len_prod = sqrtf(sup) * sqrtf(svp);
    const float EPS = 1e-6f;
    const float HI  = (float)(1.0 - 1e-6);
    float mu = 0.5f + (0.5f * dotp) / fmaxf(len_prod, EPS);
    mu = fminf(fmaxf(mu, EPS), HI);
    const float ups = fmaxf(fabsf(dotp), EPS);
    const float al0 = fmaxf(0.01f, mu * ups);
    const float be0 = fmaxf(0.01f, ups - al0);
    const float alpha = fmaxf(0.01f, (gb + al0) + uae[u] + iae[v]);
    const float beta  = fmaxf(0.01f, (gb + be0) + ube[u] + ibe[v]);
    const float am1 = alpha - 1.0f;
    const float bm1 = beta  - 1.0f;

    // ---- bin-edge chain in f64 (mask-critical), data-parallel on lanes 0..9 ---
    const double STEP = 1.0 / 63.0;
    float xf_own = 0.f, lx_own = 0.f;
    int   im_own = 0;
    {
        double e = 0.0;
        if (sub < 10)
            e = exp((double)ubt[u * 10 + sub] + (double)ibt[v * 10 + sub]);
        // inclusive scan over the 16-group (lanes >=10 contribute 0)
        double c = e;
#pragma unroll
        for (int d = 1; d < 16; d <<= 1) {
            double t = __shfl_up(c, d, 16);
            if (sub >= d) c += t;
        }
        const double ssum = __shfl(c, 9, 16);       // total of 10 terms
        if (sub < 9) {
            const double x = c / ssum;              // edge x_sub (f64)
            int im = (int)(x * 63.0);
            if (im > 62) im = 62;
            while (im < 62 && (double)(im + 1) * STEP <= x) ++im;
            while (im >= 1 && (double)im * STEP > x) --im;
            im_own = im;
            xf_own = (float)x;
            lx_own = __log2f(xf_own);
        }
    }
    // broadcast per-edge data to all 16 lanes of the group; wave-uniform m-bounds
    float xfj[9], alxj[9];
    int   imj[9], mbu[9];
#pragma unroll
    for (int j = 0; j < 9; ++j) {
        xfj[j]  = __shfl(xf_own, j, 16);
        alxj[j] = am1 * __shfl(lx_own, j, 16);
        imj[j]  = __shfl(im_own, j, 16);
        int mm  = imj[j];
        mm = max(mm, __shfl_xor(mm, 16, 64));       // max over the wave's 4 groups
        mm = max(mm, __shfl_xor(mm, 32, 64));
        mbu[j] = __builtin_amdgcn_readfirstlane((mm >> 4) + 1);  // scalar loop bound
    }

    // ---- per-lane t-points (i = m*16 + sub), exact np.linspace f32 values -----
    float tfm[4], altm[4];
#pragma unroll
    for (int m = 0; m < 4; ++m) {
        const int i = m * 16 + sub;
        const float tf = (float)((double)i * STEP);   // i=63 -> 1.0f exactly
        tfm[m]  = tf;
        altm[m] = am1 * __log2f(tf);                  // i=0 -> -inf (term -> 0)
    }

    // ---- denominator B(a,b) trapz (all 4 chunks; ends contribute 0) -----------
    float accD = 0.0f;
#pragma unroll
    for (int m = 0; m < 4; ++m) {
        const float l1 = __log2f(1.0f - tfm[m]);
        accD += exp2_fast(fmaf(bm1, l1, altm[m]));
    }

    // ---- numerators: j outer (unrolled), m inner with data-dependent bound ----
    float acc[9];
#pragma unroll
    for (int j = 0; j < 9; ++j) {
        const float xj  = xfj[j];
        const float axj = alxj[j];
        const int   imv = imj[j];
        float a = 0.0f;
        for (int m = 0; m < mbu[j]; ++m) {            // scalar bound: skips dead chunks
            const int   i  = m * 16 + sub;
            const float w  = fmaf(-tfm[m], xj, 1.0f);
            const float e  = fmaf(bm1, __log2f(w), altm[m] + axj);
            const float y  = exp2_fast(e);
            const bool  ok = (unsigned)(i - 1) < (unsigned)imv;  // 1 <= i <= im_j
            a += ok ? y : 0.0f;
        }
        acc[j] = a;
    }

    // ---- reduce the 10 sums across the 16-group -------------------------------
#pragma unroll
    for (int d = 1; d < 16; d <<= 1) {
        accD += __shfl_xor(accD, d, 64);
#pragma unroll
        for (int j = 0; j < 9; ++j) acc[j] += __shfl_xor(acc[j], d, 64);
    }

    // ---- epilogue: cdf -> mass; lanes 0..9 store ------------------------------
    const float dtf = (float)(1.0 / 63.0);
    const float Bab = accD * dtf;
    const float rB  = 1.0f / Bab;
    float cdfv[9];
#pragma unroll
    for (int j = 0; j < 9; ++j) cdfv[j] = (acc[j] * dtf) * rB;

    float mo = cdfv[0];                               // sub == 0
#pragma unroll
    for (int j = 1; j < 9; ++j) mo = (sub == j) ? (cdfv[j] - cdfv[j - 1]) : mo;
    mo = (sub == 9) ? (1.0f - cdfv[8]) : mo;
    if (valid && sub < 10) out[(long long)s * 10 + sub] = mo;
}

extern "C" void kernel_launch(void* const* d_in, const int* in_sizes, int n_in,
                              void* d_out, int out_size, void* d_ws, size_t ws_size,
                              hipStream_t stream) {
    (void)n_in; (void)out_size; (void)d_ws; (void)ws_size;
    const int*   uid = (const int*)d_in[0];
    const int*   iid = (const int*)d_in[1];
    const float* uf  = (const float*)d_in[2];
    const float* vf  = (const float*)d_in[3];
    const float* ubt = (const float*)d_in[4];
    const float* ibt = (const float*)d_in[5];
    const float* uae = (const float*)d_in[6];
    const float* ube = (const float*)d_in[7];
    const float* iae = (const float*)d_in[8];
    const float* ibe = (const float*)d_in[9];
    const float* gb  = (const float*)d_in[10];
    float* out = (float*)d_out;
    const int B = in_sizes[0];
    const int samples_per_block = BLOCK / 16;
    const int grid = (B + samples_per_block - 1) / samples_per_block;
    hipLaunchKernelGGL(lbd_kernel, dim3(grid), dim3(BLOCK), 0, stream,
                       uid, iid, uf, vf, ubt, ibt, uae, ube, iae, ibe, gb, out, B);
}

// Round 5
// 137.792 us; speedup vs baseline: 1.0166x; 1.0166x over previous
//
#include <hip/hip_runtime.h>
#include <math.h>

#define BLOCK 256
// 16 lanes cooperate on one sample; lane `sub` owns quadrature points i = m*16 + sub.
// Structure rule learned in R4: every eval must stay statically unrolled; work is
// skipped only via wave-uniform SCALAR branches around unrolled blocks.

__device__ __forceinline__ float exp2_fast(float x) {
#if __has_builtin(__builtin_amdgcn_exp2f)
    return __builtin_amdgcn_exp2f(x);   // bare v_exp_f32
#else
    return __expf(x * 0.69314718055994531f);
#endif
}

// Inline f64 exp, rel err ~7e-15 (|x| <= ~2 here). Branch-free, ~17 f64 ops vs
// libm's ~60+. Accuracy budget: x_j flip threshold needs ~1e-11; we have 7e-15.
__device__ __forceinline__ double exp_f64_fast(double x) {
    const double L2E = 1.4426950408889634074;        // log2(e)
    const double LN2 = 0.69314718055994530942;       // ln(2)
    double z = x * L2E;
    double n = rint(z);                               // v_rndne_f64
    double r = fma(x, L2E, -n);                       // |r| <= 0.5 (+eps)
    double w = r * LN2;                               // |w| <= 0.347
    double p = 2.08767569878680989792e-9;             // 1/12!
    p = fma(p, w, 2.50521083854417187751e-8);         // 1/11!
    p = fma(p, w, 2.75573192239858906526e-7);         // 1/10!
    p = fma(p, w, 2.75573192239858925110e-6);         // 1/9!
    p = fma(p, w, 2.48015873015873015873e-5);         // 1/8!
    p = fma(p, w, 1.98412698412698412698e-4);         // 1/7!
    p = fma(p, w, 1.38888888888888888889e-3);         // 1/6!
    p = fma(p, w, 8.33333333333333333333e-3);         // 1/5!
    p = fma(p, w, 4.16666666666666666667e-2);         // 1/4!
    p = fma(p, w, 1.66666666666666666667e-1);         // 1/3!
    p = fma(p, w, 0.5);
    p = fma(p, w, 1.0);
    p = fma(p, w, 1.0);
    const int ni = (int)n;                            // |n| <= 3
    const double sc = __longlong_as_double((long long)(1023 + ni) << 52);
    return p * sc;
}

__global__ __launch_bounds__(BLOCK) void lbd_kernel(
    const int* __restrict__ uid_in, const int* __restrict__ iid_in,
    const float* __restrict__ uf,  const float* __restrict__ vf,
    const float* __restrict__ ubt, const float* __restrict__ ibt,
    const float* __restrict__ uae, const float* __restrict__ ube,
    const float* __restrict__ iae, const float* __restrict__ ibe,
    const float* __restrict__ gbp, float* __restrict__ out, int B)
{
    // Sample-independent t-grid tables, once per block: (t, log2 t, log2(1-t)).
    __shared__ float4 s_tab[64];
    const int tid = threadIdx.x;
    if (tid < 64) {
        const double STEP0 = 1.0 / 63.0;
        float tf = (float)((double)tid * STEP0);      // tid=63 -> 1.0f after cast
        if (tid == 63) tf = 1.0f;
        s_tab[tid] = make_float4(tf, __log2f(tf), __log2f(1.0f - tf), 0.0f);
    }
    __syncthreads();

    const int sub = tid & 15;                         // lane within 16-lane group
    const int s0  = blockIdx.x * (BLOCK / 16) + (tid >> 4);
    const bool valid = (s0 < B);
    const int s = valid ? s0 : (B - 1);               // clamp: keep lanes live for shuffles

    const int u = uid_in[s];
    const int v = iid_in[s];

    // ---- coalesced feature gather: lane sub reads elements sub, sub+16, ... ----
    const long long ub = (long long)u * 65;
    const long long vb = (long long)v * 65;
    float fu0 = uf[ub + sub],      fv0 = vf[vb + sub];
    float fu1 = uf[ub + 16 + sub], fv1 = vf[vb + 16 + sub];
    float fu2 = uf[ub + 32 + sub], fv2 = vf[vb + 32 + sub];
    float fu3 = uf[ub + 48 + sub], fv3 = vf[vb + 48 + sub];

    float dotp = fu0 * fv0 + fu1 * fv1 + fu2 * fv2 + fu3 * fv3;
    float sup  = fu0 * fu0 + fu1 * fu1 + fu2 * fu2 + fu3 * fu3;
    float svp  = fv0 * fv0 + fv1 * fv1 + fv2 * fv2 + fv3 * fv3;
#pragma unroll
    for (int d = 1; d < 16; d <<= 1) {                // butterfly within 16-group
        dotp += __shfl_xor(dotp, d, 64);
        sup  += __shfl_xor(sup,  d, 64);
        svp  += __shfl_xor(svp,  d, 64);
    }

    // ---- alpha / beta (smooth; all 16 lanes redundantly) ----------------------
    const float gb = gbp[0];
    const float len_prod = sqrtf(sup) * sqrtf(svp);
    const float EPS = 1e-6f;
    const float HI  = (float)(1.0 - 1e-6);
    float mu = 0.5f + (0.5f * dotp) / fmaxf(len_prod, EPS);
    mu = fminf(fmaxf(mu, EPS), HI);
    const float ups = fmaxf(fabsf(dotp), EPS);
    const float al0 = fmaxf(0.01f, mu * ups);
    const float be0 = fmaxf(0.01f, ups - al0);
    const float alpha = fmaxf(0.01f, (gb + al0) + uae[u] + iae[v]);
    const float beta  = fmaxf(0.01f, (gb + be0) + ube[u] + ibe[v]);
    const float am1 = alpha - 1.0f;                   // >= ~0.96 > 0 (gb = 2.0)
    const float bm1 = beta  - 1.0f;

    // ---- bin-edge chain in f64 (mask-critical), data-parallel on lanes 0..9 ---
    const double STEP = 1.0 / 63.0;
    float xf_own = 0.f, lx_own = 0.f;
    int   im_own = 0;
    {
        double e = 0.0;
        if (sub < 10)
            e = exp_f64_fast((double)ubt[u * 10 + sub] + (double)ibt[v * 10 + sub]);
        // inclusive scan over the 16-group (lanes >=10 contribute 0)
        double c = e;
#pragma unroll
        for (int d = 1; d < 16; d <<= 1) {
            double t = __shfl_up(c, d, 16);
            if (sub >= d) c += t;
        }
        const double ssum = __shfl(c, 9, 16);         // total of 10 terms
        if (sub < 9) {
            const double x = c / ssum;                // edge x_sub (f64, IEEE div)
            int im = (int)(x * 63.0);
            if (im > 62) im = 62;
            while (im < 62 && (double)(im + 1) * STEP <= x) ++im;
            while (im >= 1 && (double)im * STEP > x) --im;
            im_own = im;
            xf_own = (float)x;
            lx_own = __log2f(xf_own);
        }
    }
    // broadcast per-edge data to group lanes; wave-uniform max-im per edge (scalar)
    float xfj[9], alxj[9];
    int   imj[9], imw[9];
#pragma unroll
    for (int j = 0; j < 9; ++j) {
        xfj[j]  = __shfl(xf_own, j, 16);
        alxj[j] = am1 * __shfl(lx_own, j, 16);
        imj[j]  = __shfl(im_own, j, 16);
        int mm  = imj[j];
        mm = max(mm, __shfl_xor(mm, 16, 64));         // max over the wave's 4 groups
        mm = max(mm, __shfl_xor(mm, 32, 64));
        imw[j] = __builtin_amdgcn_readfirstlane(mm);  // SGPR -> scalar branches below
    }

    // ---- per-lane t-points from LDS (i = m*16 + sub) --------------------------
    float tfm[4], altm[4], l1m[4];
#pragma unroll
    for (int m = 0; m < 4; ++m) {
        float4 e = s_tab[m * 16 + sub];
        tfm[m]  = e.x;
        altm[m] = am1 * e.y;                          // i=0 -> -inf (term -> 0 naturally)
        l1m[m]  = e.z;                                // i=63 -> -inf
    }

    float accD = 0.0f;
    float acc[9];
#pragma unroll
    for (int j = 0; j < 9; ++j) acc[j] = 0.0f;

    // One numerator eval: fully static (m, j) => stays unrolled, regs statically indexed.
#define EVAL_MJ(m, j)                                                              \
    do {                                                                           \
        const float w_ = fmaf(-tfm[m], xfj[j], 1.0f);                              \
        const float e_ = fmaf(bm1, __log2f(w_), altm[m] + alxj[j]);                \
        const float y_ = exp2_fast(e_);                                            \
        const int   i_ = (m) * 16 + sub;                                           \
        acc[j] += ((unsigned)(i_ - 1) < (unsigned)imj[j]) ? y_ : 0.0f;             \
    } while (0)

    // ---- denominator: all 4 chunks (ends contribute exact 0 via -inf logs) ----
#pragma unroll
    for (int m = 0; m < 4; ++m)
        accD += exp2_fast(fmaf(bm1, l1m[m], altm[m]));

    // ---- chunk m=0: always alive for every edge (straight-line, max ILP) ------
#pragma unroll
    for (int j = 0; j < 9; ++j) EVAL_MJ(0, j);

    // ---- chunks m=1..3: wave-uniform scalar guard per (m, j) ------------------
    // Skipped blocks would have contributed exact zeros -> sums bit-identical.
#pragma unroll
    for (int m = 1; m < 4; ++m) {
#pragma unroll
        for (int j = 0; j < 9; ++j) {
            if (imw[j] >= 16 * m) EVAL_MJ(m, j);
        }
    }
#undef EVAL_MJ

    // ---- reduce the 10 sums across the 16-group -------------------------------
#pragma unroll
    for (int d = 1; d < 16; d <<= 1) {
        accD += __shfl_xor(accD, d, 64);
#pragma unroll
        for (int j = 0; j < 9; ++j) acc[j] += __shfl_xor(acc[j], d, 64);
    }

    // ---- epilogue: cdf -> mass; lanes 0..9 store ------------------------------
    const float dtf = (float)(1.0 / 63.0);
    const float Bab = accD * dtf;
    const float rB  = 1.0f / Bab;
    float cdfv[9];
#pragma unroll
    for (int j = 0; j < 9; ++j) cdfv[j] = (acc[j] * dtf) * rB;

    float mo = cdfv[0];                               // sub == 0
#pragma unroll
    for (int j = 1; j < 9; ++j) mo = (sub == j) ? (cdfv[j] - cdfv[j - 1]) : mo;
    mo = (sub == 9) ? (1.0f - cdfv[8]) : mo;
    if (valid && sub < 10) out[(long long)s * 10 + sub] = mo;
}

extern "C" void kernel_launch(void* const* d_in, const int* in_sizes, int n_in,
                              void* d_out, int out_size, void* d_ws, size_t ws_size,
                              hipStream_t stream) {
    (void)n_in; (void)out_size; (void)d_ws; (void)ws_size;
    const int*   uid = (const int*)d_in[0];
    const int*   iid = (const int*)d_in[1];
    const float* uf  = (const float*)d_in[2];
    const float* vf  = (const float*)d_in[3];
    const float* ubt = (const float*)d_in[4];
    const float* ibt = (const float*)d_in[5];
    const float* uae = (const float*)d_in[6];
    const float* ube = (const float*)d_in[7];
    const float* iae = (const float*)d_in[8];
    const float* ibe = (const float*)d_in[9];
    const float* gb  = (const float*)d_in[10];
    float* out = (float*)d_out;
    const int B = in_sizes[0];
    const int samples_per_block = BLOCK / 16;
    const int grid = (B + samples_per_block - 1) / samples_per_block;
    hipLaunchKernelGGL(lbd_kernel, dim3(grid), dim3(BLOCK), 0, stream,
                       uid, iid, uf, vf, ubt, ibt, uae, ube, iae, ibe, gb, out, B);
}

// Round 6
// 132.961 us; speedup vs baseline: 1.0536x; 1.0363x over previous
//
#include <hip/hip_runtime.h>
#include <math.h>

#define BLOCK 256
// 16 lanes cooperate on one sample; lane `sub` owns quadrature points i = m*16 + sub.
// Session rules: (R4) every eval stays statically unrolled; (R5) no fine-grained
// scalar branches or LDS round-trips in the hot path — straight-line wins.

struct F4a4 { float a, b, c, d; };   // 16B load at 4B alignment -> global_load_dwordx4

__device__ __forceinline__ float exp2_fast(float x) {
#if __has_builtin(__builtin_amdgcn_exp2f)
    return __builtin_amdgcn_exp2f(x);   // bare v_exp_f32
#else
    return __expf(x * 0.69314718055994531f);
#endif
}

// Inline f64 exp, rel err ~7e-15. Proven in R5 (same absmax as libm). ~17 f64 FMAs.
__device__ __forceinline__ double exp_f64_fast(double x) {
    const double L2E = 1.4426950408889634074;        // log2(e)
    const double LN2 = 0.69314718055994530942;       // ln(2)
    double z = x * L2E;
    double n = rint(z);                               // v_rndne_f64
    double r = fma(x, L2E, -n);                       // |r| <= 0.5 (+eps)
    double w = r * LN2;                               // |w| <= 0.347
    double p = 2.08767569878680989792e-9;             // 1/12!
    p = fma(p, w, 2.50521083854417187751e-8);
    p = fma(p, w, 2.75573192239858906526e-7);
    p = fma(p, w, 2.75573192239858925110e-6);
    p = fma(p, w, 2.48015873015873015873e-5);
    p = fma(p, w, 1.98412698412698412698e-4);
    p = fma(p, w, 1.38888888888888888889e-3);
    p = fma(p, w, 8.33333333333333333333e-3);
    p = fma(p, w, 4.16666666666666666667e-2);
    p = fma(p, w, 1.66666666666666666667e-1);
    p = fma(p, w, 0.5);
    p = fma(p, w, 1.0);
    p = fma(p, w, 1.0);
    const int ni = (int)n;                            // |n| small here
    const double sc = __longlong_as_double((long long)(1023 + ni) << 52);
    return p * sc;
}

__global__ __launch_bounds__(BLOCK) void lbd_kernel(
    const int* __restrict__ uid_in, const int* __restrict__ iid_in,
    const float* __restrict__ uf,  const float* __restrict__ vf,
    const float* __restrict__ ubt, const float* __restrict__ ibt,
    const float* __restrict__ uae, const float* __restrict__ ube,
    const float* __restrict__ iae, const float* __restrict__ ibe,
    const float* __restrict__ gbp, float* __restrict__ out, int B)
{
    const int tid = threadIdx.x;
    const int sub = tid & 15;                         // lane within 16-lane group
    const int s0  = blockIdx.x * (BLOCK / 16) + (tid >> 4);
    const bool valid = (s0 < B);
    const int s = valid ? s0 : (B - 1);               // clamp: keep lanes live for shuffles

    const int u = uid_in[s];
    const int v = iid_in[s];

    // ---- feature gather: ONE dwordx4 per lane per table (elements 4*sub..4*sub+3,
    // 16 lanes cover 0..63 contiguously; element 64 is intentionally dropped) ----
    const F4a4 a = ((const F4a4*)(uf + (long long)u * 65))[sub];
    const F4a4 b = ((const F4a4*)(vf + (long long)v * 65))[sub];

    float dotp = a.a * b.a + a.b * b.b + a.c * b.c + a.d * b.d;
    float sup  = a.a * a.a + a.b * a.b + a.c * a.c + a.d * a.d;
    float svp  = b.a * b.a + b.b * b.b + b.c * b.c + b.d * b.d;
#pragma unroll
    for (int d = 1; d < 16; d <<= 1) {                // butterfly within 16-group
        dotp += __shfl_xor(dotp, d, 64);
        sup  += __shfl_xor(sup,  d, 64);
        svp  += __shfl_xor(svp,  d, 64);
    }

    // ---- alpha / beta (smooth; all 16 lanes redundantly) ----------------------
    const float gb = gbp[0];
    const float len_prod = sqrtf(sup) * sqrtf(svp);
    const float EPS = 1e-6f;
    const float HI  = (float)(1.0 - 1e-6);
    float mu = 0.5f + (0.5f * dotp) / fmaxf(len_prod, EPS);
    mu = fminf(fmaxf(mu, EPS), HI);
    const float ups = fmaxf(fabsf(dotp), EPS);
    const float al0 = fmaxf(0.01f, mu * ups);
    const float be0 = fmaxf(0.01f, ups - al0);
    const float alpha = fmaxf(0.01f, (gb + al0) + uae[u] + iae[v]);
    const float beta  = fmaxf(0.01f, (gb + be0) + ube[u] + ibe[v]);
    const float am1 = alpha - 1.0f;
    const float bm1 = beta  - 1.0f;

    // ---- bin-edge chain in f64 (mask-critical, FROZEN since R5) ---------------
    const double STEP = 1.0 / 63.0;
    float xf_own = 0.f, lx_own = 0.f;
    int   im_own = 0;
    {
        double e = 0.0;
        if (sub < 10)
            e = exp_f64_fast((double)ubt[u * 10 + sub] + (double)ibt[v * 10 + sub]);
        // inclusive scan over the 16-group (lanes >=10 contribute 0)
        double c = e;
#pragma unroll
        for (int d = 1; d < 16; d <<= 1) {
            double t = __shfl_up(c, d, 16);
            if (sub >= d) c += t;
        }
        const double ssum = __shfl(c, 9, 16);         // total of 10 terms
        if (sub < 9) {
            const double x = c / ssum;                // edge x_sub (f64, IEEE div)
            // Branch-free im = max{ i in [0,62] : i*STEP <= x }.
            // k = trunc(x*63) is within +-1 of im; one exact f64 correction each way.
            int k = (int)(x * 63.0);
            k = (k > 62) ? 62 : k;
            const int dec = ((double)k * STEP > x) ? 1 : 0;          // k too high
            const int inc = ((k < 62) && ((double)(k + 1) * STEP <= x)) ? 1 : 0; // too low
            im_own = k + inc - dec;                    // dec && inc impossible
            xf_own = (float)x;
            lx_own = __log2f(xf_own);
        }
    }
    // broadcast per-edge data to all 16 lanes of the group
    float xfj[9], alxj[9];
    int   imj[9];
#pragma unroll
    for (int j = 0; j < 9; ++j) {
        xfj[j]  = __shfl(xf_own, j, 16);
        alxj[j] = am1 * __shfl(lx_own, j, 16);
        imj[j]  = __shfl(im_own, j, 16);
    }

    // ---- per-lane t-points in registers (i = m*16 + sub), exact np f32 values --
    float tfm[4], altm[4], l1m[4];
#pragma unroll
    for (int m = 0; m < 4; ++m) {
        const int i = m * 16 + sub;
        const float tf = (float)((double)i * STEP);   // i=63 -> 1.0f exactly
        tfm[m]  = tf;
        altm[m] = am1 * __log2f(tf);                  // i=0 -> -inf (term -> 0)
        l1m[m]  = __log2f(1.0f - tf);                 // i=63 -> -inf
    }

    float accD = 0.0f;
    float acc[9];
#pragma unroll
    for (int j = 0; j < 9; ++j) acc[j] = 0.0f;

    // ---- denominator: 4 evals (ends contribute exact 0 via -inf logs) ---------
#pragma unroll
    for (int m = 0; m < 4; ++m)
        accD += exp2_fast(fmaf(bm1, l1m[m], altm[m]));

    // ---- numerators: fully unrolled straight-line 4x9 (no branches, max ILP) --
#pragma unroll
    for (int m = 0; m < 4; ++m) {
#pragma unroll
        for (int j = 0; j < 9; ++j) {
            const float w_ = fmaf(-tfm[m], xfj[j], 1.0f);
            const float e_ = fmaf(bm1, __log2f(w_), altm[m] + alxj[j]);
            const float y_ = exp2_fast(e_);
            const int   i_ = m * 16 + sub;
            acc[j] += ((unsigned)(i_ - 1) < (unsigned)imj[j]) ? y_ : 0.0f; // 1<=i<=im_j
        }
    }

    // ---- reduce the 10 sums across the 16-group -------------------------------
#pragma unroll
    for (int d = 1; d < 16; d <<= 1) {
        accD += __shfl_xor(accD, d, 64);
#pragma unroll
        for (int j = 0; j < 9; ++j) acc[j] += __shfl_xor(acc[j], d, 64);
    }

    // ---- epilogue: cdf -> mass; lanes 0..9 store ------------------------------
    const float dtf = (float)(1.0 / 63.0);
    const float Bab = accD * dtf;
    const float rB  = 1.0f / Bab;
    float cdfv[9];
#pragma unroll
    for (int j = 0; j < 9; ++j) cdfv[j] = (acc[j] * dtf) * rB;

    float mo = cdfv[0];                               // sub == 0
#pragma unroll
    for (int j = 1; j < 9; ++j) mo = (sub == j) ? (cdfv[j] - cdfv[j - 1]) : mo;
    mo = (sub == 9) ? (1.0f - cdfv[8]) : mo;
    if (valid && sub < 10) out[(long long)s * 10 + sub] = mo;
}

extern "C" void kernel_launch(void* const* d_in, const int* in_sizes, int n_in,
                              void* d_out, int out_size, void* d_ws, size_t ws_size,
                              hipStream_t stream) {
    (void)n_in; (void)out_size; (void)d_ws; (void)ws_size;
    const int*   uid = (const int*)d_in[0];
    const int*   iid = (const int*)d_in[1];
    const float* uf  = (const float*)d_in[2];
    const float* vf  = (const float*)d_in[3];
    const float* ubt = (const float*)d_in[4];
    const float* ibt = (const float*)d_in[5];
    const float* uae = (const float*)d_in[6];
    const float* ube = (const float*)d_in[7];
    const float* iae = (const float*)d_in[8];
    const float* ibe = (const float*)d_in[9];
    const float* gb  = (const float*)d_in[10];
    float* out = (float*)d_out;
    const int B = in_sizes[0];
    const int samples_per_block = BLOCK / 16;
    const int grid = (B + samples_per_block - 1) / samples_per_block;
    hipLaunchKernelGGL(lbd_kernel, dim3(grid), dim3(BLOCK), 0, stream,
                       uid, iid, uf, vf, ubt, ibt, uae, ube, iae, ibe, gb, out, B);
}

// Round 7
// 124.729 us; speedup vs baseline: 1.1231x; 1.0660x over previous
//
#include <hip/hip_runtime.h>
#include <math.h>

#define BLOCK 256
#define SPB (BLOCK / 4)   // 64 samples per block; 4 lanes cooperate per sample
// Session rules: (R4) no runtime-indexed register arrays; (R5) no fine-grained
// guards around register-resident straight-line code; (R6-fit) wave64 trans ~16cyc,
// f64 ~8cyc -> integrand-eval count dominates. This round: dynamic chunk loops with
// scalar wave-uniform bounds + LDS t-table (legal codegen shape for dynamic trips).

struct F4a4 { float a, b, c, d; };   // 16B load at 4B alignment -> global_load_dwordx4

__device__ __forceinline__ float exp2_fast(float x) {
#if __has_builtin(__builtin_amdgcn_exp2f)
    return __builtin_amdgcn_exp2f(x);   // bare v_exp_f32
#else
    return __expf(x * 0.69314718055994531f);
#endif
}

// Inline f64 exp, rel err ~7e-15. Proven R5/R6 (absmax identical to libm).
__device__ __forceinline__ double exp_f64_fast(double x) {
    const double L2E = 1.4426950408889634074;
    const double LN2 = 0.69314718055994530942;
    double n = rint(x * L2E);
    double r = fma(x, L2E, -n);
    double w = r * LN2;
    double p = 2.08767569878680989792e-9;             // 1/12!
    p = fma(p, w, 2.50521083854417187751e-8);
    p = fma(p, w, 2.75573192239858906526e-7);
    p = fma(p, w, 2.75573192239858925110e-6);
    p = fma(p, w, 2.48015873015873015873e-5);
    p = fma(p, w, 1.98412698412698412698e-4);
    p = fma(p, w, 1.38888888888888888889e-3);
    p = fma(p, w, 8.33333333333333333333e-3);
    p = fma(p, w, 4.16666666666666666667e-2);
    p = fma(p, w, 1.66666666666666666667e-1);
    p = fma(p, w, 0.5);
    p = fma(p, w, 1.0);
    p = fma(p, w, 1.0);
    const double sc = __longlong_as_double((long long)(1023 + (int)n) << 52);
    return p * sc;
}

__global__ __launch_bounds__(BLOCK) void lbd_kernel(
    const int* __restrict__ uid_in, const int* __restrict__ iid_in,
    const float* __restrict__ uf,  const float* __restrict__ vf,
    const float* __restrict__ ubt, const float* __restrict__ ibt,
    const float* __restrict__ uae, const float* __restrict__ ube,
    const float* __restrict__ iae, const float* __restrict__ ibe,
    const float* __restrict__ gbp, float* __restrict__ out, int B)
{
    // Sample-independent t-grid tables (1 KB): built once per block.
    __shared__ float2 s_num[64];   // (t_i, log2 t_i)
    __shared__ float2 s_den[64];   // (log2 t_i, log2(1-t_i))
    const int tid = threadIdx.x;
    if (tid < 64) {
        const double STEP0 = 1.0 / 63.0;
        float tf = (float)((double)tid * STEP0);      // exact np.linspace f32; tid=63 -> 1.0f
        if (tid == 63) tf = 1.0f;
        const float lt = __log2f(tf);
        const float l1 = __log2f(1.0f - tf);
        s_num[tid] = make_float2(tf, lt);
        s_den[tid] = make_float2(lt, l1);
    }
    __syncthreads();

    const int sub = tid & 3;                          // lane within 4-lane sample group
    const int s0  = blockIdx.x * SPB + (tid >> 2);
    const bool valid = (s0 < B);
    const int s = valid ? s0 : (B - 1);               // clamp: keep lanes live for shuffles

    const int u = uid_in[s];
    const int v = iid_in[s];

    // ---- feature gather: 4 x dwordx4 per table; lane covers 16c+4*sub..+3 -----
    const float* pu = uf + (long long)u * 65;
    const float* pv = vf + (long long)v * 65;
    float dotp = 0.f, sup = 0.f, svp = 0.f;
#pragma unroll
    for (int c = 0; c < 4; ++c) {
        const F4a4 a = *(const F4a4*)(pu + c * 16 + sub * 4);
        const F4a4 b = *(const F4a4*)(pv + c * 16 + sub * 4);
        dotp += a.a * b.a + a.b * b.b + a.c * b.c + a.d * b.d;
        sup  += a.a * a.a + a.b * a.b + a.c * a.c + a.d * a.d;
        svp  += b.a * b.a + b.b * b.b + b.c * b.c + b.d * b.d;
    }
#pragma unroll
    for (int d = 1; d < 4; d <<= 1) {                 // butterfly within 4-group
        dotp += __shfl_xor(dotp, d, 64);
        sup  += __shfl_xor(sup,  d, 64);
        svp  += __shfl_xor(svp,  d, 64);
    }

    // ---- alpha / beta (smooth; 4 lanes redundantly) ---------------------------
    const float gb = gbp[0];
    const float len_prod = sqrtf(sup) * sqrtf(svp);
    const float EPS = 1e-6f;
    const float HI  = (float)(1.0 - 1e-6);
    float mu = 0.5f + (0.5f * dotp) / fmaxf(len_prod, EPS);
    mu = fminf(fmaxf(mu, EPS), HI);
    const float ups = fmaxf(fabsf(dotp), EPS);
    const float al0 = fmaxf(0.01f, mu * ups);
    const float be0 = fmaxf(0.01f, ups - al0);
    const float alpha = fmaxf(0.01f, (gb + al0) + uae[u] + iae[v]);
    const float beta  = fmaxf(0.01f, (gb + be0) + ube[u] + ibe[v]);
    const float am1 = alpha - 1.0f;                   // > 0 (gb = 2.0)
    const float bm1 = beta  - 1.0f;                   // > 0

    // ---- bin-edge chain in f64 (mask-critical; slop-tolerant per R2->R3 evidence)
    // Lane sub owns contiguous bins lb..lb+2 (lane3: bin 9 only).
    const double STEP = 1.0 / 63.0;
    const int lb = 3 * sub;
    double e0, e1 = 0.0, e2 = 0.0;
    {
        const long long ur = (long long)u * 10, vr = (long long)v * 10;
        const int i1 = (lb + 1 <= 9) ? lb + 1 : 9;    // clamp to stay in-bounds
        const int i2 = (lb + 2 <= 9) ? lb + 2 : 9;
        e0 = exp_f64_fast((double)ubt[ur + lb] + (double)ibt[vr + lb]);
        const double t1 = exp_f64_fast((double)ubt[ur + i1] + (double)ibt[vr + i1]);
        const double t2 = exp_f64_fast((double)ubt[ur + i2] + (double)ibt[vr + i2]);
        if (lb + 1 <= 9) e1 = t1;                     // lane3 contributes only bin 9
        if (lb + 2 <= 9) e2 = t2;
    }
    const double c0 = e0, c1 = c0 + e1, c2 = c1 + e2; // local cumsum (3 bins)
    double p = c2;                                    // local total
#pragma unroll
    for (int d = 1; d < 4; d <<= 1) {                 // inclusive scan of totals
        const double t = __shfl_up(p, d, 4);
        if (sub >= d) p += t;
    }
    const double ssum = __shfl(p, 3, 4);              // grand total (10 bins)
    const double ex   = p - c2;                       // exclusive prefix
    // own edges at static slots r=0..2 (global edge index lb+r, valid if <= 8)
    float xf_own[3] = {0.f, 0.f, 0.f}, lx_own[3] = {0.f, 0.f, 0.f};
    int   im_own[3] = {0, 0, 0};
    const double cg0 = ex + c0, cg1 = ex + c1, cg2 = ex + c2;
#pragma unroll
    for (int r = 0; r < 3; ++r) {
        const double cgr = (r == 0) ? cg0 : (r == 1) ? cg1 : cg2;
        if (lb + r <= 8) {
            const double x = cgr / ssum;              // IEEE f64 div
            int k = (int)(x * 63.0);
            k = (k > 62) ? 62 : k;
            const int dec = ((double)k * STEP > x) ? 1 : 0;
            const int inc = ((k < 62) && ((double)(k + 1) * STEP <= x)) ? 1 : 0;
            im_own[r] = k + inc - dec;                // exact im, branch-free
            xf_own[r] = (float)x;
            lx_own[r] = __log2f(xf_own[r]);
        }
    }

    // ---- broadcast edges to the 4-group; wave-uniform scalar chunk bounds -----
    float xfj[9], alxj[9];
    int   imj[9], Mw[9];
#pragma unroll
    for (int j = 0; j < 9; ++j) {
        const int src  = j / 3;                       // compile-time
        const int slot = j % 3;                       // compile-time
        const float xo = (slot == 0) ? xf_own[0] : (slot == 1) ? xf_own[1] : xf_own[2];
        const float lo = (slot == 0) ? lx_own[0] : (slot == 1) ? lx_own[1] : lx_own[2];
        const int   io = (slot == 0) ? im_own[0] : (slot == 1) ? im_own[1] : im_own[2];
        xfj[j]  = __shfl(xo, src, 4);
        alxj[j] = am1 * __shfl(lo, src, 4);
        imj[j]  = __shfl(io, src, 4);
        int mm = imj[j];
        mm = max(mm, __shfl_xor(mm, 4, 64));          // max over the wave's 16 groups
        mm = max(mm, __shfl_xor(mm, 8, 64));
        mm = max(mm, __shfl_xor(mm, 16, 64));
        mm = max(mm, __shfl_xor(mm, 32, 64));
        Mw[j] = __builtin_amdgcn_readfirstlane((mm >> 2) + 1);  // scalar trip count
    }

    // ---- denominator: 16 static evals from LDS (ends -> exact 0 via -inf) -----
    float accD = 0.f;
#pragma unroll
    for (int m = 0; m < 16; ++m) {
        const float2 dd = s_den[m * 4 + sub];
        accD += exp2_fast(fmaf(bm1, dd.y, am1 * dd.x));
    }

    // ---- numerators: 9 loops, scalar wave-uniform trips, LDS t-table ----------
    float acc[9];
#pragma unroll
    for (int j = 0; j < 9; ++j) {
        const float xj  = xfj[j];
        const float axj = alxj[j];
        const int   imv = imj[j];
        const int   M   = Mw[j];
        float a0 = 0.f;
        for (int m = 0; m < M; ++m) {                 // trip 1..16, wave-uniform scalar
            const int i = m * 4 + sub;
            const float2 tl = s_num[i];               // broadcast-heavy ds_read_b64
            const float w = fmaf(-tl.x, xj, 1.0f);    // > 0 always (t,x < 1)
            const float e = fmaf(bm1, __log2f(w), fmaf(am1, tl.y, axj));
            const float y = exp2_fast(e);
            a0 += ((unsigned)(i - 1) < (unsigned)imv) ? y : 0.f;  // 1 <= i <= im_j
        }
        acc[j] = a0;
    }

    // ---- reduce across the 4-group --------------------------------------------
#pragma unroll
    for (int d = 1; d < 4; d <<= 1) {
        accD += __shfl_xor(accD, d, 64);
#pragma unroll
        for (int j = 0; j < 9; ++j) acc[j] += __shfl_xor(acc[j], d, 64);
    }

    // ---- epilogue: cdf -> mass; lane sub stores indices {sub, sub+4, sub+8} ---
    const float dtf = (float)(1.0 / 63.0);
    const float rB  = 1.0f / (accD * dtf);
    float cdfv[9];
#pragma unroll
    for (int j = 0; j < 9; ++j) cdfv[j] = (acc[j] * dtf) * rB;

    const float o0 = (sub == 0) ? cdfv[0]
                   : (sub == 1) ? (cdfv[1] - cdfv[0])
                   : (sub == 2) ? (cdfv[2] - cdfv[1])
                   :              (cdfv[3] - cdfv[2]);
    const float o1 = (sub == 0) ? (cdfv[4] - cdfv[3])
                   : (sub == 1) ? (cdfv[5] - cdfv[4])
                   : (sub == 2) ? (cdfv[6] - cdfv[5])
                   :              (cdfv[7] - cdfv[6]);
    const float o2 = (sub == 0) ? (cdfv[8] - cdfv[7])
                   :              (1.0f - cdfv[8]);   // sub==1; sub>=2 unused
    if (valid) {
        const long long ob = (long long)s * 10;
        out[ob + sub]     = o0;
        out[ob + 4 + sub] = o1;
        if (sub < 2) out[ob + 8 + sub] = o2;
    }
}

extern "C" void kernel_launch(void* const* d_in, const int* in_sizes, int n_in,
                              void* d_out, int out_size, void* d_ws, size_t ws_size,
                              hipStream_t stream) {
    (void)n_in; (void)out_size; (void)d_ws; (void)ws_size;
    const int*   uid = (const int*)d_in[0];
    const int*   iid = (const int*)d_in[1];
    const float* uf  = (const float*)d_in[2];
    const float* vf  = (const float*)d_in[3];
    const float* ubt = (const float*)d_in[4];
    const float* ibt = (const float*)d_in[5];
    const float* uae = (const float*)d_in[6];
    const float* ube = (const float*)d_in[7];
    const float* iae = (const float*)d_in[8];
    const float* ibe = (const float*)d_in[9];
    const float* gb  = (const float*)d_in[10];
    float* out = (float*)d_out;
    const int B = in_sizes[0];
    const int grid = (B + SPB - 1) / SPB;
    hipLaunchKernelGGL(lbd_kernel, dim3(grid), dim3(BLOCK), 0, stream,
                       uid, iid, uf, vf, ubt, ibt, uae, ube, iae, ibe, gb, out, B);
}